// Round 5
// baseline (712.825 us; speedup 1.0000x reference)
//
#include <hip/hip_runtime.h>
#include <math.h>

// FNO2d: B=8, H=W=128, WIDTH=32, MODES=12, NL=6
// Spectral conv via partial DFT with register-rotator twiddles.
// Head: fc1+fc3 fused in one MFMA kernel (bf16 hi/lo x3); fc4+fc5 fp32.

#define NL 6

typedef unsigned short u16;
typedef __attribute__((ext_vector_type(8))) short short8v;
typedef __attribute__((ext_vector_type(8))) unsigned short ushort8v;
typedef __attribute__((ext_vector_type(4))) unsigned short ushort4v;
typedef __attribute__((ext_vector_type(4))) float f32x4;

__device__ __forceinline__ float gelu_f(float x){
  return 0.5f*x*(1.0f + erff(x*0.70710678118654752f));
}
__device__ __forceinline__ u16 f2bf(float x){
  unsigned u = __float_as_uint(x);
  u += 0x7FFF + ((u>>16)&1);
  return (u16)(u>>16);
}
__device__ __forceinline__ float bf2f(u16 h){
  return __uint_as_float(((unsigned)h)<<16);
}

// ---------------- fc0: x[B,H,W,4] @ [4,32] + b -> y[B,32,H,W] ----------------
__global__ __launch_bounds__(256) void k_fc0(const float* __restrict__ x,
                      const float* __restrict__ W, const float* __restrict__ b,
                      float* __restrict__ y){
  __shared__ float Ws[128];
  __shared__ float bs[32];
  int t = threadIdx.x;
  if (t < 128) Ws[t] = W[t];
  if (t < 32)  bs[t] = b[t];
  __syncthreads();
  int pix = blockIdx.x*256 + t;
  float4 xv = *reinterpret_cast<const float4*>(x + (size_t)pix*4);
  int bb = pix >> 14, hw = pix & 16383;
  float* yp = y + (size_t)bb*32*16384 + hw;
  #pragma unroll
  for (int c=0;c<32;c++){
    float acc = bs[c] + xv.x*Ws[c] + xv.y*Ws[32+c] + xv.z*Ws[64+c] + xv.w*Ws[96+c];
    yp[(size_t)c*16384] = acc;
  }
}

// ------- one-time weight transpose: spec_w[l][hf][i][o][kym][kx][ri] ------
// -> wT[l][hf][kym][kx][i][o][ri]
__global__ __launch_bounds__(256) void k_wtrans(const float* __restrict__ w, float* __restrict__ wT){
  __shared__ float buf[16][32][25];
  int t=threadIdx.x;
  int beta = blockIdx.x;            // 6*2*12*2 = 288
  int l = beta/48, r = beta%48;
  int hf = r/24; int r2 = r%24;
  int kym = r2>>1; int i0 = (r2&1)*16;
  const float* src = w + (size_t)l*589824 + (size_t)hf*294912 + kym*24;
  float* dst = wT + (size_t)l*589824 + (size_t)hf*294912 + (size_t)kym*24576;
  for (int j=t; j<12288; j+=256){
    int i = j/768, rem = j%768, o = rem/24, kxri = rem%24;
    buf[i][o][kxri] = src[(size_t)(i0+i)*9216 + o*288 + kxri];
  }
  __syncthreads();
  for (int j=t; j<12288; j+=256){
    int kx = j>>10, rem = j&1023, i = rem>>6, orr = rem&63, o = orr>>1, ri = orr&1;
    dst[(size_t)kx*2048 + (i0+i)*64 + o*2 + ri] = buf[i][o][kx*2+ri];
  }
}

// ------- head weight prep: W1[32,256]->W1T[n][32] h/l; W3[256,128]->W3T[n][256] h/l
__global__ __launch_bounds__(256) void k_wprep(const float* __restrict__ W1, const float* __restrict__ W3,
                       u16* __restrict__ W1h, u16* __restrict__ W1l,
                       u16* __restrict__ W3h, u16* __restrict__ W3l){
  __shared__ float buf[32][132];
  int t = threadIdx.x, bid = blockIdx.x;   // 9 blocks
  if (bid < 8){
    int k0 = bid*32;
    for (int i=t;i<4096;i+=256){ int k=i>>7, n=i&127; buf[k][n] = W3[(size_t)(k0+k)*128 + n]; }
    __syncthreads();
    int n = t>>1, kq = t&1;
    #pragma unroll
    for (int kk=0;kk<16;kk++){
      int k = kq*16 + kk;
      float v = buf[k][n];
      u16 hh = f2bf(v);
      W3h[(size_t)n*256 + k0 + k] = hh;
      W3l[(size_t)n*256 + k0 + k] = f2bf(v - bf2f(hh));
    }
  } else {
    int n = t;
    #pragma unroll
    for (int c=0;c<32;c++){
      float v = W1[(size_t)c*256 + n];
      u16 hh = f2bf(v);
      W1h[n*32 + c] = hh;
      W1l[n*32 + c] = f2bf(v - bf2f(hh));
    }
  }
}

// ---------- fused 2D forward DFT: y[b][c][h][w] -> F2[b*32+c][kyi][kxri] ----
__global__ __launch_bounds__(256) void k_dft2d(const float* __restrict__ y, float* __restrict__ F2){
  __shared__ float xs[128][132];
  __shared__ float T1[128][28];
  __shared__ float P2[4800];     // [kx][ri][hg][kyi(25)]
  int t = threadIdx.x;
  int bc = blockIdx.x;           // 256
  for (int i=t;i<16384;i+=256){ xs[i>>7][i&127] = y[(size_t)bc*16384 + i]; }
  __syncthreads();
  // phase A: W-direction, 12 kx modes, register rotators
  {
    int h = t>>1, wg = t&1;
    float cr[12], ci[12], aR[12], aI[12], stc[12], sts[12];
    #pragma unroll
    for (int k=0;k<12;k++){
      aR[k]=0.f; aI[k]=0.f;
      cr[k] = ((k&1)&&wg)? -1.f : 1.f; ci[k]=0.f;
      float s,c; sincospif(k*(1.0f/64.0f), &s, &c); stc[k]=c; sts[k]=s;
    }
    const float* xrow = &xs[h][wg*64];
    for (int q=0;q<16;q++){
      float4 xq = *reinterpret_cast<const float4*>(&xrow[q*4]);
      float xa[4] = {xq.x,xq.y,xq.z,xq.w};
      #pragma unroll
      for (int e=0;e<4;e++){
        float xw = xa[e];
        #pragma unroll
        for (int k=0;k<12;k++){
          aR[k] += xw*cr[k];
          aI[k] -= xw*ci[k];
          float nc = cr[k]*stc[k] - ci[k]*sts[k];
          ci[k]    = cr[k]*sts[k] + ci[k]*stc[k];
          cr[k] = nc;
        }
      }
    }
    #pragma unroll
    for (int k=0;k<12;k++){
      aR[k] += __shfl_xor(aR[k], 1);
      aI[k] += __shfl_xor(aI[k], 1);
    }
    __syncthreads();
    #pragma unroll
    for (int q=0;q<6;q++){
      int k = wg*6+q;
      T1[h][2*k]   = aR[k];
      T1[h][2*k+1] = aI[k];
    }
  }
  __syncthreads();
  // phase B: H-direction, 24 ky modes
  {
    int kyi = t&31, hg = t>>5;
    if (kyi < 24){
      int ky = (kyi<12)? kyi : kyi+104;
      float aR[12], aI[12];
      #pragma unroll
      for (int k=0;k<12;k++){ aR[k]=0.f; aI[k]=0.f; }
      float sc,ss; sincospif(ky*(1.0f/64.0f), &ss, &sc);
      float c0,s0; sincospif((float)(ky*hg)*0.25f, &s0, &c0);
      for (int hh=0; hh<16; hh++){
        int h = hg*16+hh;
        float a[24];
        #pragma unroll
        for (int q=0;q<6;q++) *reinterpret_cast<float4*>(&a[q*4]) = *reinterpret_cast<const float4*>(&T1[h][q*4]);
        #pragma unroll
        for (int k=0;k<12;k++){
          aR[k] += a[2*k]*c0 + a[2*k+1]*s0;
          aI[k] += a[2*k+1]*c0 - a[2*k]*s0;
        }
        float nc = c0*sc - s0*ss; s0 = c0*ss + s0*sc; c0 = nc;
      }
      #pragma unroll
      for (int k=0;k<12;k++){
        P2[((k*2+0)*8+hg)*25 + kyi] = aR[k];
        P2[((k*2+1)*8+hg)*25 + kyi] = aI[k];
      }
    }
  }
  __syncthreads();
  for (int j=t; j<576; j+=256){
    int kyi = j/24, col = j%24;
    float s = 0.f;
    #pragma unroll
    for (int hg=0;hg<8;hg++) s += P2[(col*8+hg)*25 + kyi];
    F2[(size_t)bc*576 + kyi*24 + col] = s;
  }
}

// ---------------- mode mix with transposed weights --------------------------
// F2[b*32+c][kyi][kxri] x wT -> G2[b][kyi][col(2kx+ri)][o]
__global__ __launch_bounds__(256) void k_mix(const float* __restrict__ F2, const float* __restrict__ wTl,
                     float* __restrict__ G2){
  __shared__ float fr[12][33], fi[12][33];
  int t=threadIdx.x;
  int kyi = blockIdx.x>>3, b = blockIdx.x&7;   // 192 blocks
  for (int j=t; j<768; j+=256){
    int c = j/24, col = j%24;
    float v = F2[((size_t)(b*32+c)*24 + kyi)*24 + col];
    if (col&1) fi[col>>1][c] = v; else fr[col>>1][c] = v;
  }
  __syncthreads();
  int hf = kyi<12?0:1, kym = kyi<12?kyi:kyi-12;
  const float* wb = wTl + (size_t)(hf*12+kym)*24576;
  for (int j=t; j<384; j+=256){
    int o = j&31, kx = j>>5;
    const float* wp = wb + kx*2048 + o*2;
    float gr=0.f, gi=0.f;
    #pragma unroll 8
    for (int i=0;i<32;i++){
      float2 wv = *reinterpret_cast<const float2*>(&wp[i*64]);
      float ar = fr[kx][i], ai = fi[kx][i];
      gr += ar*wv.x - ai*wv.y;
      gi += ar*wv.y + ai*wv.x;
    }
    size_t gidx = ((size_t)(b*24 + kyi)*24 + kx*2)*32 + o;
    G2[gidx] = gr; G2[gidx+32] = gi;
  }
}

// --------- combine: fused inverse-H DFT (from G2) + inverse-W DFT + conv1x1 +
//           bias terms + GELU. LAST=1 emits y as bf16 hi/lo [pix][32].
template<int LAST>
__global__ __launch_bounds__(256) void k_combine(const float* __restrict__ yin, const float* __restrict__ G2,
                         const float* __restrict__ x,
                         const float* __restrict__ wWl, const float* __restrict__ wbl,
                         const float* __restrict__ bWl, const float* __restrict__ bbl,
                         const float* __restrict__ cWl, const float* __restrict__ cbl,
                         float* __restrict__ yout,
                         u16* __restrict__ yh, u16* __restrict__ yl){
  __shared__ float ysT[128][33];
  __shared__ float s1[32][25];
  __shared__ float cw[24], sw[24];
  int t=threadIdx.x;
  int b = blockIdx.x>>7, h = blockIdx.x&127;
  if (t<24){ int ky = t<12? t : t+104;
    float s,c; sincospif((float)(ky*h)*(1.0f/64.0f), &s, &c); cw[t]=c; sw[t]=s; }
  for (int i=t;i<4096;i+=256){ int c=i>>7, w=i&127;
    ysT[w][c] = yin[(((size_t)(b*32+c))*128+h)*128+w]; }
  __syncthreads();
  // inverse-H DFT: s1[o][col] from G2 (L2-resident)
  #pragma unroll
  for (int j=t; j<768; j+=256){
    int o = j&31, col = j>>5;
    int kx2 = col & ~1;
    const float* gp = G2 + (size_t)b*18432 + kx2*32 + o;
    bool isIm = col&1;
    float acc = 0.f;
    #pragma unroll
    for (int kyi=0;kyi<24;kyi++){
      float Gr = gp[kyi*768];
      float Gi = gp[kyi*768 + 32];
      float re = Gr*cw[kyi] - Gi*sw[kyi];
      float im = Gr*sw[kyi] + Gi*cw[kyi];
      acc += isIm ? im : re;
    }
    s1[o][col] = acc*(1.0f/16384.0f);
  }
  __syncthreads();
  int w = t&127;
  int og = __builtin_amdgcn_readfirstlane(t>>7);   // wave-uniform 0/1
  float xv[32];
  #pragma unroll
  for (int c=0;c<32;c++) xv[c] = ysT[w][c];
  float ct[12], st[12];
  ct[0]=1.f; st[0]=0.f;
  float c1,s1v; sincospif(w*(1.0f/64.0f), &s1v, &c1);
  #pragma unroll
  for (int k=0;k<11;k++){ ct[k+1] = ct[k]*c1 - st[k]*s1v; st[k+1] = ct[k]*s1v + st[k]*c1; }
  float gx = h*(1.0f/127.0f), gy = w*(1.0f/127.0f);
  float4 xm = *reinterpret_cast<const float4*>(x + (((size_t)(b*128+h))*128+w)*4);
  float m1=xm.y, m2=xm.z, m3=xm.w;
  const float* wo  = wWl + og*512;                 // [16][32]
  float accv[16];
  #pragma unroll
  for (int oi=0;oi<16;oi++){
    int o = og*16+oi;
    float bse = wbl[o] + bbl[o] + cbl[o] + gx*bWl[o*2] + gy*bWl[o*2+1]
              + m1*cWl[o*3] + m2*cWl[o*3+1] + m3*cWl[o*3+2];
    float spec = s1[o][0];
    #pragma unroll
    for (int kx=1;kx<12;kx++) spec += 2.0f*(s1[o][2*kx]*ct[kx] - s1[o][2*kx+1]*st[kx]);
    accv[oi] = bse + spec;
  }
  #pragma unroll
  for (int c=0;c<32;c++){
    float xc = xv[c];
    #pragma unroll
    for (int oi=0;oi<16;oi++) accv[oi] += wo[oi*32+c]*xc;
  }
  if constexpr (!LAST){
    #pragma unroll
    for (int oi=0;oi<16;oi++){
      int o = og*16+oi;
      yout[(((size_t)(b*32+o))*128+h)*128+w] = gelu_f(accv[oi]);
    }
  } else {
    __syncthreads();     // all ysT reads done (xv in regs); reuse ysT as [w][o]
    #pragma unroll
    for (int oi=0;oi<16;oi++) ysT[w][og*16+oi] = gelu_f(accv[oi]);
    __syncthreads();
    int wr = t>>1, hf2 = t&1;
    size_t pix = (size_t)b*16384 + h*128 + wr;
    ushort8v h8a, l8a, h8b, l8b;
    #pragma unroll
    for (int q=0;q<8;q++){
      float v = ysT[wr][hf2*16 + q];
      u16 hh = f2bf(v);
      h8a[q] = hh; l8a[q] = f2bf(v - bf2f(hh));
      float v2 = ysT[wr][hf2*16 + 8 + q];
      u16 hh2 = f2bf(v2);
      h8b[q] = hh2; l8b[q] = f2bf(v2 - bf2f(hh2));
    }
    *reinterpret_cast<ushort8v*>(yh + pix*32 + hf2*16)     = h8a;
    *reinterpret_cast<ushort8v*>(yh + pix*32 + hf2*16 + 8) = h8b;
    *reinterpret_cast<ushort8v*>(yl + pix*32 + hf2*16)     = l8a;
    *reinterpret_cast<ushort8v*>(yl + pix*32 + hf2*16 + 8) = l8b;
  }
}

// ------- fused head fc1+fc3 via MFMA bf16x3 -> A2[n3][p] fp32, GELU --------
__global__ __launch_bounds__(256) void k_headm(
    const u16* __restrict__ Yh, const u16* __restrict__ Yl,     // [pix][32]
    const u16* __restrict__ W1h, const u16* __restrict__ W1l,   // [256][32]
    const float* __restrict__ b1,
    const u16* __restrict__ W3h, const u16* __restrict__ W3l,   // [128][256]
    const float* __restrict__ b3,
    float* __restrict__ A2){
  __shared__ u16 Ylh[128][40], Yll[128][40];
  __shared__ u16 Ach[128][40], Acl[128][40];
  __shared__ u16 W3ch[128][40], W3cl[128][40];
  __shared__ float b1s[256];
  __shared__ float b3s[128];
  int t = threadIdx.x;
  int wv = t>>6, lane = t&63, lr = lane&15, lg = lane>>4;
  int P0 = blockIdx.x*128;
  b1s[t] = b1[t];
  if (t<128) b3s[t] = b3[t];
  {
    int row = t>>1, off = (t&1)*16;
    const u16* s0 = Yh + (size_t)(P0+row)*32 + off;
    *reinterpret_cast<ushort8v*>(&Ylh[row][off])   = *reinterpret_cast<const ushort8v*>(s0);
    *reinterpret_cast<ushort8v*>(&Ylh[row][off+8]) = *reinterpret_cast<const ushort8v*>(s0+8);
    const u16* s1p = Yl + (size_t)(P0+row)*32 + off;
    *reinterpret_cast<ushort8v*>(&Yll[row][off])   = *reinterpret_cast<const ushort8v*>(s1p);
    *reinterpret_cast<ushort8v*>(&Yll[row][off+8]) = *reinterpret_cast<const ushort8v*>(s1p+8);
  }
  int wn3 = wv>>1, wp = wv&1;
  int p0w = wv*32;
  f32x4 acc3[4][4];
  #pragma unroll
  for (int i=0;i<4;i++)
    #pragma unroll
    for (int j=0;j<4;j++) acc3[i][j] = (f32x4){0.f,0.f,0.f,0.f};
  __syncthreads();

  for (int kt=0; kt<8; ++kt){
    // ---- issue W3 chunk loads (written to LDS below) ----
    int srow = t>>1, soff = (t&1)*16;
    const u16* g3h = W3h + (size_t)srow*256 + kt*32 + soff;
    const u16* g3l = W3l + (size_t)srow*256 + kt*32 + soff;
    ushort8v wh0 = *reinterpret_cast<const ushort8v*>(g3h);
    ushort8v wh1 = *reinterpret_cast<const ushort8v*>(g3h+8);
    ushort8v wl0 = *reinterpret_cast<const ushort8v*>(g3l);
    ushort8v wl1 = *reinterpret_cast<const ushort8v*>(g3l+8);
    // ---- fc1: A1 chunk [128p][32n1] ----
    short8v ybh[2], ybl[2];
    #pragma unroll
    for (int j=0;j<2;j++){
      int p = p0w + j*16 + lr;
      ybh[j] = *reinterpret_cast<const short8v*>(&Ylh[p][lg*8]);
      ybl[j] = *reinterpret_cast<const short8v*>(&Yll[p][lg*8]);
    }
    f32x4 a1[2][2];
    #pragma unroll
    for (int i=0;i<2;i++)
      #pragma unroll
      for (int j=0;j<2;j++) a1[i][j] = (f32x4){0.f,0.f,0.f,0.f};
    #pragma unroll
    for (int i=0;i<2;i++){
      int n1 = kt*32 + i*16 + lr;
      short8v w1f = *reinterpret_cast<const short8v*>(W1h + (size_t)n1*32 + lg*8);
      short8v w1g = *reinterpret_cast<const short8v*>(W1l + (size_t)n1*32 + lg*8);
      #pragma unroll
      for (int j=0;j<2;j++){
        a1[i][j] = __builtin_amdgcn_mfma_f32_16x16x32_bf16(w1f, ybh[j], a1[i][j], 0,0,0);
        a1[i][j] = __builtin_amdgcn_mfma_f32_16x16x32_bf16(w1f, ybl[j], a1[i][j], 0,0,0);
        a1[i][j] = __builtin_amdgcn_mfma_f32_16x16x32_bf16(w1g, ybh[j], a1[i][j], 0,0,0);
      }
    }
    // gelu + split -> Ac chunk LDS ([p][n1loc]); D rows=n1(4lg+reg), cols=p(lr)
    #pragma unroll
    for (int i=0;i<2;i++){
      int n1b = kt*32 + i*16 + 4*lg;
      #pragma unroll
      for (int j=0;j<2;j++){
        int p = p0w + j*16 + lr;
        ushort4v hv, lv;
        #pragma unroll
        for (int r=0;r<4;r++){
          float v = gelu_f(a1[i][j][r] + b1s[n1b+r]);
          u16 hh = f2bf(v);
          hv[r] = hh; lv[r] = f2bf(v - bf2f(hh));
        }
        *reinterpret_cast<ushort4v*>(&Ach[p][i*16+4*lg]) = hv;
        *reinterpret_cast<ushort4v*>(&Acl[p][i*16+4*lg]) = lv;
      }
    }
    // ---- write W3 chunk ----
    *reinterpret_cast<ushort8v*>(&W3ch[srow][soff])   = wh0;
    *reinterpret_cast<ushort8v*>(&W3ch[srow][soff+8]) = wh1;
    *reinterpret_cast<ushort8v*>(&W3cl[srow][soff])   = wl0;
    *reinterpret_cast<ushort8v*>(&W3cl[srow][soff+8]) = wl1;
    __syncthreads();
    // ---- fc3 accumulate ----
    short8v abh[4], abl[4];
    #pragma unroll
    for (int j=0;j<4;j++){
      int pb = wp*64 + j*16 + lr;
      abh[j] = *reinterpret_cast<const short8v*>(&Ach[pb][lg*8]);
      abl[j] = *reinterpret_cast<const short8v*>(&Acl[pb][lg*8]);
    }
    #pragma unroll
    for (int i=0;i<4;i++){
      int n3 = wn3*64 + i*16 + lr;
      short8v w3f = *reinterpret_cast<const short8v*>(&W3ch[n3][lg*8]);
      short8v w3g = *reinterpret_cast<const short8v*>(&W3cl[n3][lg*8]);
      #pragma unroll
      for (int j=0;j<4;j++){
        acc3[i][j] = __builtin_amdgcn_mfma_f32_16x16x32_bf16(w3f, abh[j], acc3[i][j], 0,0,0);
        acc3[i][j] = __builtin_amdgcn_mfma_f32_16x16x32_bf16(w3f, abl[j], acc3[i][j], 0,0,0);
        acc3[i][j] = __builtin_amdgcn_mfma_f32_16x16x32_bf16(w3g, abh[j], acc3[i][j], 0,0,0);
      }
    }
    __syncthreads();
  }
  // epilogue: D rows=n3 (4lg+reg), cols=p (lr); A2[n3][131072p]
  #pragma unroll
  for (int i=0;i<4;i++){
    int n3b = wn3*64 + i*16 + 4*lg;
    #pragma unroll
    for (int j=0;j<4;j++){
      int p = P0 + wp*64 + j*16 + lr;
      #pragma unroll
      for (int r=0;r<4;r++){
        A2[(size_t)(n3b+r)*131072 + p] = gelu_f(acc3[i][j][r] + b3s[n3b+r]);
      }
    }
  }
}

// ------ fused fc4+fc5: A2[k][p] @ W4[128,128]+b4, dot w5, +b5 -> out[p] -----
__global__ __launch_bounds__(256) void k_last(const float* __restrict__ A, const float* __restrict__ W4,
                   const float* __restrict__ b4, const float* __restrict__ w5,
                   const float* __restrict__ b5, float* __restrict__ out){
  __shared__ __align__(16) float As[32][132];
  __shared__ __align__(16) float Bs[32][132];
  __shared__ float b4s[128], w5s[128];
  __shared__ float part[4][128];
  int t=threadIdx.x;
  if (t<128){ b4s[t]=b4[t]; w5s[t]=w5[t]; }
  size_t p0 = (size_t)blockIdx.x*128;
  int tx=t&15, ty=t>>4;
  float acc[8][8]={};
  for (int kc=0;kc<128;kc+=32){
    for (int i=t;i<1024;i+=256){ int k=i>>5, f=i&31;
      *reinterpret_cast<float4*>(&As[k][f*4]) =
        *reinterpret_cast<const float4*>(&A[(size_t)(kc+k)*131072 + p0 + f*4]); }
    for (int i=t;i<1024;i+=256){ int k=i>>5, f=i&31;
      *reinterpret_cast<float4*>(&Bs[k][f*4]) =
        *reinterpret_cast<const float4*>(&W4[(size_t)(kc+k)*128 + f*4]); }
    __syncthreads();
    #pragma unroll 8
    for (int k=0;k<32;k++){
      float a[8], bb[8];
      *reinterpret_cast<float4*>(a)    = *reinterpret_cast<const float4*>(&As[k][tx*4]);
      *reinterpret_cast<float4*>(a+4)  = *reinterpret_cast<const float4*>(&As[k][64+tx*4]);
      *reinterpret_cast<float4*>(bb)   = *reinterpret_cast<const float4*>(&Bs[k][ty*4]);
      *reinterpret_cast<float4*>(bb+4) = *reinterpret_cast<const float4*>(&Bs[k][64+ty*4]);
      #pragma unroll
      for (int i=0;i<8;i++)
        #pragma unroll
        for (int j=0;j<8;j++) acc[i][j] += a[i]*bb[j];
    }
    __syncthreads();
  }
  float s[8];
  #pragma unroll
  for (int i=0;i<8;i++){
    float si = 0.f;
    #pragma unroll
    for (int j=0;j<8;j++){
      int n = (j<4)? ty*4+j : 64+ty*4+(j-4);
      si += (acc[i][j] + b4s[n]) * w5s[n];
    }
    si += __shfl_xor(si, 16);
    si += __shfl_xor(si, 32);
    s[i] = si;
  }
  int wv = t>>6;
  if ((t&63) < 16){
    #pragma unroll
    for (int i=0;i<8;i++){
      int m = (i<4)? tx*4+i : 64+tx*4+(i-4);
      part[wv][m] = s[i];
    }
  }
  __syncthreads();
  if (t<128){
    out[p0 + t] = part[0][t]+part[1][t]+part[2][t]+part[3][t] + b5[0];
  }
}

extern "C" void kernel_launch(void* const* d_in, const int* in_sizes, int n_in,
                              void* d_out, int out_size, void* d_ws, size_t ws_size,
                              hipStream_t stream){
  const float* x     = (const float*)d_in[0];
  const float* fc0_W = (const float*)d_in[1];
  const float* fc0_b = (const float*)d_in[2];
  const float* spec_w= (const float*)d_in[3];
  const float* wW    = (const float*)d_in[4];
  const float* wb    = (const float*)d_in[5];
  const float* bW    = (const float*)d_in[6];
  const float* bb    = (const float*)d_in[7];
  const float* cW    = (const float*)d_in[8];
  const float* cb    = (const float*)d_in[9];
  const float* fc1_W = (const float*)d_in[10];
  const float* fc1_b = (const float*)d_in[11];
  const float* fc3_W = (const float*)d_in[12];
  const float* fc3_b = (const float*)d_in[13];
  const float* fc4_W = (const float*)d_in[14];
  const float* fc4_b = (const float*)d_in[15];
  const float* fc5_W = (const float*)d_in[16];
  const float* fc5_b = (const float*)d_in[17];
  float* out = (float*)d_out;
  float* ws  = (float*)d_ws;

  float* y_a = ws;                         // 4,194,304
  float* y_b = y_a + 4194304;              // 4,194,304
  float* wT  = y_b + 4194304;              // 3,538,944
  float* F2  = wT + 3538944;               //   147,456
  float* G2  = F2 + 147456;                //   147,456  (end 12,222,464)
  // overlays (stream-ordered):
  u16*   Yhh = (u16*)y_a;                  // final-layer y hi  [pix][32] (4.19M u16)
  u16*   Yll_ = (u16*)y_a + 4194304;       // final-layer y lo
  float* A2  = y_b;                        // 16,777,216 floats (overlaps wT/F2/G2, dead)
  float* WP  = ws + 20971520;              // head weight prep region
  u16*   W1h = (u16*)WP;                   //  8,192 u16
  u16*   W1l = W1h + 8192;
  u16*   W3h = W1l + 8192;                 // 32,768 u16
  u16*   W3l = W3h + 32768;                // end ~21.0M floats

  k_fc0<<<512,256,0,stream>>>(x, fc0_W, fc0_b, y_a);
  k_wtrans<<<288,256,0,stream>>>(spec_w, wT);
  k_wprep<<<9,256,0,stream>>>(fc1_W, fc3_W, W1h, W1l, W3h, W3l);

  for (int l=0;l<NL;l++){
    float* yin  = (l&1)? y_b : y_a;
    float* yout = (l&1)? y_a : y_b;
    k_dft2d<<<256,256,0,stream>>>(yin, F2);
    k_mix<<<192,256,0,stream>>>(F2, wT + (size_t)l*589824, G2);
    if (l < NL-1){
      k_combine<0><<<1024,256,0,stream>>>(yin, G2, x,
                                     wW + (size_t)l*1024, wb + (size_t)l*32,
                                     bW + (size_t)l*64,  bb + (size_t)l*32,
                                     cW + (size_t)l*96,  cb + (size_t)l*32,
                                     yout, nullptr, nullptr);
    } else {
      k_combine<1><<<1024,256,0,stream>>>(yin, G2, x,
                                     wW + (size_t)l*1024, wb + (size_t)l*32,
                                     bW + (size_t)l*64,  bb + (size_t)l*32,
                                     cW + (size_t)l*96,  cb + (size_t)l*32,
                                     nullptr, Yhh, Yll_);
    }
  }

  k_headm<<<1024,256,0,stream>>>(Yhh, Yll_, W1h, W1l, fc1_b, W3h, W3l, fc3_b, A2);
  k_last<<<1024,256,0,stream>>>(A2, fc4_W, fc4_b, fc5_W, fc5_b, out);
}